// Round 1
// baseline (336.963 us; speedup 1.0000x reference)
//
#include <hip/hip_runtime.h>

// expRNN/modReLU recurrence:
//   B=8192, T=784, I=1, H=30, C=10
//   h_{t+1} = sign(z)*relu(|z|+b),  z = W_hh h_t + W_ih x_t
//   out     = h_T @ W_lin^T + b_lin
//
// Layout (round 1):
//   - 1024 blocks x 64 threads (single wave per block -> wave-synchronous,
//     no barriers in the T loop; DS ops are in-order per wave and each
//     lane's LDS read range may-alias its write range, so program order holds).
//   - Each block owns 8 batch elements. lane = bb*8 + g:
//       bb = l>>3 : local batch (0..7)
//       g  = l&7  : row group; lane computes rows 4g..4g+3
//   - W_hh row (augmented to 32 cols: col30 = W_ih, col31 = 0) lives in
//     128 VGPRs per lane, loaded once. x_t is folded in as h[30].
//   - h per batch in LDS, padded to 36 floats (16B aligned, conflict-free).
//   - all x for the block's 8 batches preloaded to LDS (25 KB). Total LDS
//     26.2 KB/block -> 4 blocks/CU fits (104 KB < 160 KB).

#define T_STEPS 784
#define NBATCH  8192
#define NH      30
#define NC      10
#define BPB     8     // batches per block
#define HP      36    // padded h row length (floats), 144 B = 16B aligned

__global__ __launch_bounds__(64, 1)
void rnn_modrelu_kernel(const float* __restrict__ inp,    // [B, T, 1]
                        const float* __restrict__ W_ih,   // [H, 1]
                        const float* __restrict__ W_hh,   // [H, H]
                        const float* __restrict__ b_mod,  // [H]
                        const float* __restrict__ W_lin,  // [C, H]
                        const float* __restrict__ b_lin,  // [C]
                        float* __restrict__ out)          // [B, C]
{
    __shared__ __align__(16) float xl[BPB * T_STEPS];  // x tile for 8 batches
    __shared__ __align__(16) float hl[BPB * HP];       // h state, padded rows

    const int l   = threadIdx.x;   // 0..63
    const int blk = blockIdx.x;    // 0..1023
    const int g   = l & 7;         // row group within batch
    const int bb  = l >> 3;        // local batch index 0..7

    // ---- preload x: 8 batches x 784 floats = 1568 float4, coalesced ----
    {
        const float4* src = (const float4*)(inp + (size_t)blk * (BPB * T_STEPS));
        float4* dst = (float4*)xl;
        #pragma unroll
        for (int k = 0; k < 25; ++k) {
            int idx = l + 64 * k;
            if (idx < (BPB * T_STEPS) / 4) dst[idx] = src[idx];
        }
    }

    // ---- load augmented W rows 4g..4g+3 into registers ----
    float w[4][32];
    float bm[4];
    #pragma unroll
    for (int r = 0; r < 4; ++r) {
        const int row = 4 * g + r;
        const bool act = (row < NH);
        bm[r] = act ? b_mod[row] : 0.0f;
        #pragma unroll
        for (int j = 0; j < 32; ++j) {
            float v = 0.0f;
            if (act) {
                if (j < NH)       v = W_hh[row * NH + j];
                else if (j == NH) v = W_ih[row];   // x coefficient
            }
            w[r][j] = v;
        }
    }

    // ---- init h = 0, h[30] slot = x_0 ----
    for (int k = l; k < BPB * HP; k += 64) hl[k] = 0.0f;
    __syncthreads();
    if (g == 0) hl[bb * HP + NH] = xl[bb * T_STEPS + 0];
    __syncthreads();

    float* hb = &hl[bb * HP];

    // ---- recurrence ----
    #pragma unroll 1
    for (int t = 0; t < T_STEPS; ++t) {
        float z[4] = {0.0f, 0.0f, 0.0f, 0.0f};

        #pragma unroll
        for (int jj = 0; jj < 8; ++jj) {
            const float4 hv = *(const float4*)(hb + 4 * jj);
            #pragma unroll
            for (int r = 0; r < 4; ++r) {
                z[r] = fmaf(w[r][4 * jj + 0], hv.x, z[r]);
                z[r] = fmaf(w[r][4 * jj + 1], hv.y, z[r]);
                z[r] = fmaf(w[r][4 * jj + 2], hv.z, z[r]);
                z[r] = fmaf(w[r][4 * jj + 3], hv.w, z[r]);
            }
        }

        // modReLU: sign(z)*relu(|z|+b). Pad rows have w==0,b==0 -> stay 0.
        float hn[4];
        #pragma unroll
        for (int r = 0; r < 4; ++r) {
            float a = fabsf(z[r]) + bm[r];
            a = fmaxf(a, 0.0f);
            hn[r] = copysignf(a, z[r]);
        }

        // write own 4 rows (g==7 writes pad slots 30,31 as zero; the x
        // writer below then overwrites slot 30 -> later DS op wins in-order)
        *(float4*)(hb + 4 * g) = make_float4(hn[0], hn[1], hn[2], hn[3]);
        if (g == 0 && t + 1 < T_STEPS) {
            hb[NH] = xl[bb * T_STEPS + (t + 1)];
        }
        // single-wave block: DS pipe is in-order per wave; next iteration's
        // reads may-alias these writes, so no barrier needed.
    }

    __syncthreads();

    // ---- classifier head: 80 outputs (8 batches x 10 classes) ----
    #pragma unroll
    for (int it = 0; it < 2; ++it) {
        const int k = l + 64 * it;
        if (k < BPB * NC) {
            const int bbo = k / NC;
            const int c   = k % NC;
            float acc = b_lin[c];
            #pragma unroll
            for (int i = 0; i < NH; ++i) {
                acc = fmaf(W_lin[c * NH + i], hl[bbo * HP + i], acc);
            }
            out[((size_t)blk * BPB + bbo) * NC + c] = acc;
        }
    }
}

extern "C" void kernel_launch(void* const* d_in, const int* in_sizes, int n_in,
                              void* d_out, int out_size, void* d_ws, size_t ws_size,
                              hipStream_t stream) {
    const float* inp   = (const float*)d_in[0];
    const float* W_ih  = (const float*)d_in[1];
    const float* W_hh  = (const float*)d_in[2];
    const float* b_mod = (const float*)d_in[3];
    const float* W_lin = (const float*)d_in[4];
    const float* b_lin = (const float*)d_in[5];
    float* out = (float*)d_out;

    dim3 grid(NBATCH / BPB);   // 1024 blocks
    dim3 block(64);            // one wave
    rnn_modrelu_kernel<<<grid, block, 0, stream>>>(inp, W_ih, W_hh, b_mod,
                                                   W_lin, b_lin, out);
}